// Round 6
// baseline (406.352 us; speedup 1.0000x reference)
//
#include <hip/hip_runtime.h>
#include <cstdint>

// Problem constants
#define BATCH   2
#define T_SEQ   2048
#define NH      16
#define DK      128
#define DMODEL  2048   // NH*DK
#define NQKV    6144   // 3*DMODEL

using short8 = __attribute__((ext_vector_type(8))) short;   // 8 bf16 (4 VGPRs)
using f32x4  = __attribute__((ext_vector_type(4))) float;   // 16x16 MFMA C/D
using f32x16 = __attribute__((ext_vector_type(16))) float;  // 32x32 MFMA C/D

__device__ __forceinline__ float bf2f(unsigned short u) {
    union { float f; uint32_t i; } x; x.i = ((uint32_t)u) << 16; return x.f;
}
__device__ __forceinline__ unsigned short f2bf(float f) {
    union { float f; uint32_t i; } x; x.f = f;
    uint32_t r = x.i + 0x7fffu + ((x.i >> 16) & 1u);   // RNE (no NaN inputs here)
    return (unsigned short)(r >> 16);
}

// async global->LDS, 16B per lane. LDS dest = wave-uniform base + lane*16 (m104/m108).
__device__ __forceinline__ void async_load16(const unsigned short* g, unsigned short* l) {
    __builtin_amdgcn_global_load_lds(
        (const __attribute__((address_space(1))) unsigned int*)g,
        (__attribute__((address_space(3))) unsigned int*)l,
        16, 0, 0);
}

// ---------------------------------------------------------------- prep kernels

__global__ void cast_x_kernel(const float* __restrict__ x,
                              unsigned short* __restrict__ xb, int n4) {
    int i = blockIdx.x * 256 + threadIdx.x;
    if (i >= n4) return;
    float4 v = ((const float4*)x)[i];
    ushort4 o;
    o.x = f2bf(v.x); o.y = f2bf(v.y); o.z = f2bf(v.z); o.w = f2bf(v.w);
    ((ushort4*)xb)[i] = o;
}

// W (K,N) fp32 row-major -> WT (N,K) bf16 row-major (for gemm_bt B-frag reads)
__global__ void wtrans_kernel(const float* __restrict__ W,
                              unsigned short* __restrict__ WT, int K, int N) {
    __shared__ unsigned short tile[64][65];  // +1 pad
    int k0 = blockIdx.y * 64, n0 = blockIdx.x * 64;
    for (int it = 0; it < 16; ++it) {
        int idx = it * 256 + threadIdx.x;
        int r = idx >> 6, c = idx & 63;                       // r: k-row, c: n-col
        tile[r][c] = f2bf(W[(size_t)(k0 + r) * N + n0 + c]);  // coalesced in n
    }
    __syncthreads();
    for (int it = 0; it < 16; ++it) {
        int idx = it * 256 + threadIdx.x;
        int r = idx >> 6, c = idx & 63;                       // r: n-row of WT, c: k-col
        WT[(size_t)(n0 + r) * K + k0 + c] = tile[c][r];       // coalesced in k
    }
}

// ---------------------------------------------------------------- GEMM
// 128x128 tile, BK=64, 4 waves 2x2, 32x32x16 MFMA, 32 KiB LDS -> 3 blocks/CU
// (implicit wave-overlap, m114). At the m97-structure ceiling (~873 TF).
// NOTE (r5 post-mortem): SQ_LDS_BANK_CONFLICT = 4.0/ds_read_b128 is invariant
// to the row-bit XOR permutation (1.258e7 with ^(row&7) AND with
// ^(row&7)^((row>>2)&6)) — structural to the l31-row/lhi-slot read shape,
// not fixable by slot permutation. Accepted (~5us).
template <int MODE>
__global__ __launch_bounds__(256) void gemm_bt_kernel(
    const unsigned short* __restrict__ A, const unsigned short* __restrict__ BT,
    float* __restrict__ Cout,
    unsigned short* __restrict__ qraw, unsigned short* __restrict__ kraw,
    unsigned short* __restrict__ vtb,
    int M, int N, int K) {
    __shared__ __align__(16) unsigned short As[128 * 64];
    __shared__ __align__(16) unsigned short Bs[128 * 64];
    const int tid = threadIdx.x;
    const int w = tid >> 6, lane = tid & 63;
    const int l31 = lane & 31, lhi = lane >> 5;
    const int m0 = blockIdx.y * 128, n0 = blockIdx.x * 128;
    const int wm = (w & 1) * 64, wn = (w >> 1) * 64;

    f32x16 acc[2][2];
#pragma unroll
    for (int a = 0; a < 2; ++a)
#pragma unroll
        for (int b = 0; b < 2; ++b)
#pragma unroll
            for (int r = 0; r < 16; ++r) acc[a][b][r] = 0.f;

    const int gsw = (l31 & 7) ^ ((l31 >> 2) & 6);

    for (int k0 = 0; k0 < K; k0 += 64) {
#pragma unroll
        for (int j = 0; j < 4; ++j) {
            int c   = (w * 4 + j) * 64 + lane;   // chunk id 0..1023
            int row = c >> 3;
            int kcg = (c & 7) ^ (row & 7) ^ ((row >> 2) & 6);  // swizzled source chunk
            async_load16(A  + (size_t)(m0 + row) * K + k0 + kcg * 8,
                         As + (size_t)(w * 4 + j) * 64 * 8);
            async_load16(BT + (size_t)(n0 + row) * K + k0 + kcg * 8,
                         Bs + (size_t)(w * 4 + j) * 64 * 8);
        }
        __syncthreads();   // drains vmcnt for global_load_lds
#pragma unroll
        for (int ks = 0; ks < 4; ++ks) {         // 4 k-steps of 16
            short8 af[2], bfr[2];
#pragma unroll
            for (int mt = 0; mt < 2; ++mt) {
                int row = wm + mt * 32 + l31;
                int kcs = (ks * 2 + lhi) ^ gsw;
                af[mt] = *(const short8*)(As + row * 64 + kcs * 8);
            }
#pragma unroll
            for (int nt = 0; nt < 2; ++nt) {
                int row = wn + nt * 32 + l31;
                int kcs = (ks * 2 + lhi) ^ gsw;
                bfr[nt] = *(const short8*)(Bs + row * 64 + kcs * 8);
            }
#pragma unroll
            for (int mt = 0; mt < 2; ++mt)
#pragma unroll
                for (int nt = 0; nt < 2; ++nt)
                    acc[mt][nt] = __builtin_amdgcn_mfma_f32_32x32x16_bf16(
                        af[mt], bfr[nt], acc[mt][nt], 0, 0, 0);
        }
        __syncthreads();
    }

    if (MODE == 0) {
#pragma unroll
        for (int mt = 0; mt < 2; ++mt)
#pragma unroll
            for (int nt = 0; nt < 2; ++nt)
#pragma unroll
                for (int r = 0; r < 16; ++r) {
                    int row = m0 + wm + mt * 32 + (r & 3) + 8 * (r >> 2) + 4 * lhi;
                    int col = n0 + wn + nt * 32 + l31;
                    Cout[(size_t)row * N + col] = acc[mt][nt][r];
                }
    } else {
        // qkv column -> head h = col/384; within-head: [0,128) q, [128,256) k,
        // [256,384) v. 32-col tiles never straddle sections (128 % 32 == 0).
#pragma unroll
        for (int mt = 0; mt < 2; ++mt) {
            int trowb = m0 + wm + mt * 32;      // 32-row tile, within one batch
            int bi = trowb >> 11;
            int tb = trowb & (T_SEQ - 1);
#pragma unroll
            for (int nt = 0; nt < 2; ++nt) {
                int colb = n0 + wn + nt * 32;
                int h    = colb / 384;
                int r3   = colb - h * 384;
                int sec  = r3 >> 7;
                int dk   = (r3 & 127) + l31;
                if (sec < 2) {
                    unsigned short* dst = (sec == 0 ? qraw : kraw) +
                        ((size_t)(bi * NH + h) * T_SEQ + tb) * DK + dk;
#pragma unroll
                    for (int r = 0; r < 16; ++r) {
                        int t = (r & 3) + 8 * (r >> 2) + 4 * lhi;
                        dst[(size_t)t * DK] = f2bf(acc[mt][nt][r]);
                    }
                } else {
                    // V stored transposed (B,H,DK,T): regs 4g..4g+3 are 4
                    // consecutive t -> one 8B store per group
                    unsigned short* dst =
                        vtb + ((size_t)(bi * NH + h) * DK + dk) * T_SEQ + tb;
#pragma unroll
                    for (int g = 0; g < 4; ++g) {
                        ushort4 p;
                        p.x = f2bf(acc[mt][nt][4 * g + 0]);
                        p.y = f2bf(acc[mt][nt][4 * g + 1]);
                        p.z = f2bf(acc[mt][nt][4 * g + 2]);
                        p.w = f2bf(acc[mt][nt][4 * g + 3]);
                        *(ushort4*)(dst + 8 * g + 4 * lhi) = p;
                    }
                }
            }
        }
    }
}

// ---------------------------------------------------------------- RoPE (in place)
__global__ void rope_kernel(unsigned short* __restrict__ qraw,
                            unsigned short* __restrict__ kraw,
                            const float* __restrict__ freqs) {
    int linear = blockIdx.x * 256 + threadIdx.x;   // ((b*NH+h)*T + t)*64 + i
    int i  = linear & 63;
    int t  = (linear >> 6) & (T_SEQ - 1);
    int bh = linear >> 17;
    int b  = bh >> 4;
    float f  = freqs[((size_t)b * T_SEQ + t) * 64 + i];
    float cs = __cosf(f), sn = __sinf(f);
    size_t off = ((size_t)bh * T_SEQ + t) * DK + 2 * i;
    ushort2 qp = *(ushort2*)(qraw + off);
    ushort2 kp = *(ushort2*)(kraw + off);
    float qr = bf2f(qp.x), qi = bf2f(qp.y);
    float kr = bf2f(kp.x), ki = bf2f(kp.y);
    ushort2 qo, ko;
    qo.x = f2bf(qr * cs - qi * sn); qo.y = f2bf(qr * sn + qi * cs);
    ko.x = f2bf(kr * cs - ki * sn); ko.y = f2bf(kr * sn + ki * cs);
    *(ushort2*)(qraw + off) = qo;
    *(ushort2*)(kraw + off) = ko;
}

// ---------------------------------------------------------------- flash attention
// Round-6: 128 q-rows per block (two 64-row GROUPS), 4 waves, wave owns
// 16 rows per group. Per KV-iter the block now amortizes {syncthreads,
// vmcnt drain, staging issue, K-frag LDS reads (bk row-invariant -> read
// once, feed both groups), KV HBM/L2 stream} over 2x the rows. LDS
// unchanged (72.7 KB -> 2 blocks/CU). Grid (32 bh, 16 qt), 512 blocks.
// Causality: group 0 = rows [q0, q0+64) -> diag tile kt==2qt, fully
// masked (skipped) at kt==2qt+1; group 1 = rows [q0+64, q0+128) -> diag
// at kt==2qt+1, unmasked before. All branches wave-uniform.
// pbuf reused by groups sequentially: per-wave DS ops are in-order and
// ap-reads are lgkmcnt(0)-waited before group-1 writes -> no hazard.
__global__ __launch_bounds__(256) void attn_kernel(
    const unsigned short* __restrict__ qb, const unsigned short* __restrict__ kb,
    const unsigned short* __restrict__ vt, unsigned short* __restrict__ ctx) {
    __shared__ __align__(16) unsigned short Ks[2][64 * 128];   // [key][dk]   2x16 KB
    __shared__ __align__(16) unsigned short Vs[2][128 * 64];   // [dk][key]   2x16 KB
    __shared__ __align__(16) unsigned short pbuf[4][16 * 68];  // stride 68: 2-way banks
    const int qt   = 15 - blockIdx.y;               // heavy tiles dispatched first
    const int u    = blockIdx.x;
    const int bh   = ((u & 7) << 2) | (u >> 3);     // same head -> same XCD (id%8)
    const int q0   = qt * 128;
    const int w    = threadIdx.x >> 6, lane = threadIdx.x & 63;
    const int lrow = lane & 15, quad = lane >> 4;
    const int ktm  = 2 * qt + 1;                    // last kv tile
    const float sc2 = 0.08838834764831845f * 1.4426950408889634f;  // DK^-.5 * log2e
    const short8 vone = {16256, 16256, 16256, 16256, 16256, 16256, 16256, 16256}; // bf16 1.0

    // Q A-frags for both groups (A[m=lane&15][k=quad*8+j], 4 k-chunks of 32)
    short8 aq[2][4];
#pragma unroll
    for (int g = 0; g < 2; ++g) {
        const unsigned short* qbase =
            qb + ((size_t)bh * T_SEQ + q0 + 64 * g + w * 16 + lrow) * DK;
#pragma unroll
        for (int kk = 0; kk < 4; ++kk)
            aq[g][kk] = *(const short8*)(qbase + kk * 32 + quad * 8);
    }

    f32x4 o[2][8];
#pragma unroll
    for (int g = 0; g < 2; ++g)
#pragma unroll
        for (int d = 0; d < 8; ++d) o[g][d] = (f32x4){0.f, 0.f, 0.f, 0.f};
    f32x4 ol[2];
    ol[0] = (f32x4){0.f, 0.f, 0.f, 0.f};
    ol[1] = (f32x4){0.f, 0.f, 0.f, 0.f};

    const unsigned short* kg0 = kb + (size_t)bh * T_SEQ * DK;
    const unsigned short* vg0 = vt + (size_t)bh * DK * T_SEQ;

    auto stage = [&](int kt, int sbuf) {
        const unsigned short* kg = kg0 + (size_t)kt * 64 * DK;
        const unsigned short* vg = vg0 + kt * 64;
        unsigned short* Kd = &Ks[sbuf][0];
        unsigned short* Vd = &Vs[sbuf][0];
#pragma unroll
        for (int j = 0; j < 4; ++j) {
            int c = (w * 4 + j) * 64 + lane;            // 0..1023
            int kr_ = c >> 4, kc = (c & 15) ^ (kr_ & 7);
            async_load16(kg + (size_t)kr_ * DK + kc * 8, Kd + c * 8);
            int vr = c >> 3, vc = (c & 7) ^ (vr & 7);
            async_load16(vg + (size_t)vr * T_SEQ + vc * 8, Vd + c * 8);
        }
    };

// softmax numerator + PV for one group. SARR: f32x4[4] scores; G: group idx;
// DIAG: apply causal mask relative to this group's 64-row window.
#define SMPV(SARR, G, DIAG)                                                     \
  {                                                                             \
    const bool diag_ = (DIAG);                                                  \
    unsigned short* pb = &pbuf[w][0];                                           \
    _Pragma("unroll") for (int nt = 0; nt < 4; ++nt)                            \
      _Pragma("unroll") for (int r = 0; r < 4; ++r) {                           \
        float p = exp2f(fmaf(SARR[nt][r], sc2, -12.0f));                        \
        if (diag_ && (nt * 16 + lrow > w * 16 + quad * 4 + r)) p = 0.f;         \
        pb[(quad * 4 + r) * 68 + nt * 16 + lrow] = f2bf(p);                     \
      }                                                                         \
    __builtin_amdgcn_s_waitcnt(0xc07f);  /* lgkmcnt(0): P writes visible */     \
    short8 ap[2];                                                               \
    _Pragma("unroll") for (int kk2 = 0; kk2 < 2; ++kk2)                         \
      ap[kk2] = *(const short8*)(pb + lrow * 68 + kk2 * 32 + quad * 8);         \
    _Pragma("unroll") for (int kk2 = 0; kk2 < 2; ++kk2)                         \
      ol[G] = __builtin_amdgcn_mfma_f32_16x16x32_bf16(ap[kk2], vone, ol[G],     \
                                                      0, 0, 0);                 \
    _Pragma("unroll") for (int d = 0; d < 8; ++d)                               \
      _Pragma("unroll") for (int kk2 = 0; kk2 < 2; ++kk2) {                     \
        int row = d * 16 + lrow;                                                \
        int vc = (kk2 * 4 + quad) ^ (row & 7);                                  \
        short8 bv = *(const short8*)(Vb + row * 64 + vc * 8);                   \
        o[G][d] = __builtin_amdgcn_mfma_f32_16x16x32_bf16(ap[kk2], bv,          \
                                                          o[G][d], 0, 0, 0);    \
      }                                                                         \
  }

    stage(0, 0);
    for (int kt = 0; kt <= ktm; ++kt) {
        __syncthreads();   // drains own vmcnt (incl. stage(kt)) then syncs waves
        if (kt < ktm) stage(kt + 1, (kt + 1) & 1);
        const unsigned short* Kb = &Ks[kt & 1][0];
        const unsigned short* Vb = &Vs[kt & 1][0];

        if (kt <= 2 * qt) {
            // ---- fused QK for both groups: bk read ONCE, used twice
            f32x4 s[2][4];
#pragma unroll
            for (int g = 0; g < 2; ++g)
#pragma unroll
                for (int nt = 0; nt < 4; ++nt) s[g][nt] = (f32x4){0.f, 0.f, 0.f, 0.f};
#pragma unroll
            for (int kk = 0; kk < 4; ++kk)
#pragma unroll
                for (int nt = 0; nt < 4; ++nt) {
                    int row = nt * 16 + lrow;
                    int kc = (kk * 4 + quad) ^ (row & 7);
                    short8 bk = *(const short8*)(Kb + row * 128 + kc * 8);
                    s[0][nt] = __builtin_amdgcn_mfma_f32_16x16x32_bf16(
                        aq[0][kk], bk, s[0][nt], 0, 0, 0);
                    s[1][nt] = __builtin_amdgcn_mfma_f32_16x16x32_bf16(
                        aq[1][kk], bk, s[1][nt], 0, 0, 0);
                }
            SMPV(s[0], 0, kt == 2 * qt)
            SMPV(s[1], 1, false)
        } else {
            // kt == 2qt+1: group 0 fully masked (skip); group 1 diag tile
            f32x4 s1[4];
#pragma unroll
            for (int nt = 0; nt < 4; ++nt) s1[nt] = (f32x4){0.f, 0.f, 0.f, 0.f};
#pragma unroll
            for (int kk = 0; kk < 4; ++kk)
#pragma unroll
                for (int nt = 0; nt < 4; ++nt) {
                    int row = nt * 16 + lrow;
                    int kc = (kk * 4 + quad) ^ (row & 7);
                    short8 bk = *(const short8*)(Kb + row * 128 + kc * 8);
                    s1[nt] = __builtin_amdgcn_mfma_f32_16x16x32_bf16(
                        aq[1][kk], bk, s1[nt], 0, 0, 0);
                }
            SMPV(s1, 1, true)
        }
    }
#undef SMPV

    // epilogue: ctx (b, t, h*DK+dk) bf16 ; divide by row sum (shift cancels)
    const int b = bh >> 4, h = bh & 15;
#pragma unroll
    for (int g = 0; g < 2; ++g) {
        float rl[4];
#pragma unroll
        for (int r = 0; r < 4; ++r) rl[r] = 1.0f / ol[g][r];
#pragma unroll
        for (int d = 0; d < 8; ++d)
#pragma unroll
            for (int r = 0; r < 4; ++r) {
                int row = q0 + 64 * g + w * 16 + quad * 4 + r;
                ctx[((size_t)(b * T_SEQ + row)) * DMODEL + h * DK + d * 16 + lrow] =
                    f2bf(o[g][d][r] * rl[r]);
            }
    }
}

// ---------------------------------------------------------------- launch
extern "C" void kernel_launch(void* const* d_in, const int* in_sizes, int n_in,
                              void* d_out, int out_size, void* d_ws, size_t ws_size,
                              hipStream_t stream) {
    const float* x     = (const float*)d_in[0];
    const float* freqs = (const float*)d_in[1];
    const float* Wqkv  = (const float*)d_in[2];
    const float* Wout  = (const float*)d_in[3];
    float* out = (float*)d_out;
    char* ws = (char*)d_ws;
    // workspace layout (96 MiB total); ctx aliases xb (dead after GEMM1)
    unsigned short* xb    = (unsigned short*)(ws);               // 16 MiB
    unsigned short* ctx   = (unsigned short*)(ws);               // 16 MiB (alias)
    unsigned short* wqkvT = (unsigned short*)(ws + 16777216);    // 24 MiB
    unsigned short* woutT = (unsigned short*)(ws + 41943040);    // 8 MiB
    unsigned short* qraw  = (unsigned short*)(ws + 50331648);    // 16 MiB
    unsigned short* kraw  = (unsigned short*)(ws + 67108864);    // 16 MiB
    unsigned short* vtb   = (unsigned short*)(ws + 83886080);    // 16 MiB

    cast_x_kernel<<<8192, 256, 0, stream>>>(x, xb, 2097152);
    wtrans_kernel<<<dim3(96, 32), 256, 0, stream>>>(Wqkv, wqkvT, DMODEL, NQKV);
    wtrans_kernel<<<dim3(32, 32), 256, 0, stream>>>(Wout, woutT, DMODEL, DMODEL);
    gemm_bt_kernel<1><<<dim3(48, 32), 256, 0, stream>>>(
        xb, wqkvT, nullptr, qraw, kraw, vtb, BATCH * T_SEQ, NQKV, DMODEL);
    rope_kernel<<<16384, 256, 0, stream>>>(qraw, kraw, freqs);
    attn_kernel<<<dim3(32, 16), 256, 0, stream>>>(qraw, kraw, vtb, ctx);
    gemm_bt_kernel<0><<<dim3(16, 32), 256, 0, stream>>>(
        ctx, woutT, out, nullptr, nullptr, nullptr, BATCH * T_SEQ, DMODEL, DMODEL);
}

// Round 7
// 389.127 us; speedup vs baseline: 1.0443x; 1.0443x over previous
//
#include <hip/hip_runtime.h>
#include <cstdint>

// Problem constants
#define BATCH   2
#define T_SEQ   2048
#define NH      16
#define DK      128
#define DMODEL  2048   // NH*DK
#define NQKV    6144   // 3*DMODEL

using short8 = __attribute__((ext_vector_type(8))) short;   // 8 bf16 (4 VGPRs)
using f32x4  = __attribute__((ext_vector_type(4))) float;   // 16x16 MFMA C/D
using f32x16 = __attribute__((ext_vector_type(16))) float;  // 32x32 MFMA C/D

__device__ __forceinline__ float bf2f(unsigned short u) {
    union { float f; uint32_t i; } x; x.i = ((uint32_t)u) << 16; return x.f;
}
__device__ __forceinline__ unsigned short f2bf(float f) {
    union { float f; uint32_t i; } x; x.f = f;
    uint32_t r = x.i + 0x7fffu + ((x.i >> 16) & 1u);   // RNE (no NaN inputs here)
    return (unsigned short)(r >> 16);
}

// async global->LDS, 16B per lane. LDS dest = wave-uniform base + lane*16 (m104/m108).
__device__ __forceinline__ void async_load16(const unsigned short* g, unsigned short* l) {
    __builtin_amdgcn_global_load_lds(
        (const __attribute__((address_space(1))) unsigned int*)g,
        (__attribute__((address_space(3))) unsigned int*)l,
        16, 0, 0);
}

// ---------------------------------------------------------------- prep kernels

__global__ void cast_x_kernel(const float* __restrict__ x,
                              unsigned short* __restrict__ xb, int n4) {
    int i = blockIdx.x * 256 + threadIdx.x;
    if (i >= n4) return;
    float4 v = ((const float4*)x)[i];
    ushort4 o;
    o.x = f2bf(v.x); o.y = f2bf(v.y); o.z = f2bf(v.z); o.w = f2bf(v.w);
    ((ushort4*)xb)[i] = o;
}

// W (K,N) fp32 row-major -> WT (N,K) bf16 row-major (for gemm_bt B-frag reads)
__global__ void wtrans_kernel(const float* __restrict__ W,
                              unsigned short* __restrict__ WT, int K, int N) {
    __shared__ unsigned short tile[64][65];  // +1 pad
    int k0 = blockIdx.y * 64, n0 = blockIdx.x * 64;
    for (int it = 0; it < 16; ++it) {
        int idx = it * 256 + threadIdx.x;
        int r = idx >> 6, c = idx & 63;                       // r: k-row, c: n-col
        tile[r][c] = f2bf(W[(size_t)(k0 + r) * N + n0 + c]);  // coalesced in n
    }
    __syncthreads();
    for (int it = 0; it < 16; ++it) {
        int idx = it * 256 + threadIdx.x;
        int r = idx >> 6, c = idx & 63;                       // r: n-row of WT, c: k-col
        WT[(size_t)(n0 + r) * K + k0 + c] = tile[c][r];       // coalesced in k
    }
}

// ---------------------------------------------------------------- GEMM
// 128x128 tile, BK=64, 4 waves 2x2, 32x32x16 MFMA, 32 KiB LDS -> 3 blocks/CU
// (implicit wave-overlap, m114). At the m97-structure ceiling (~873 TF).
// SQ_LDS_BANK_CONFLICT = 4.0/ds_read_b128 is structural to the l31-row read
// shape (invariant to slot permutation, r5) — accepted (~5us).
template <int MODE>
__global__ __launch_bounds__(256) void gemm_bt_kernel(
    const unsigned short* __restrict__ A, const unsigned short* __restrict__ BT,
    float* __restrict__ Cout,
    unsigned short* __restrict__ qraw, unsigned short* __restrict__ kraw,
    unsigned short* __restrict__ vtb,
    int M, int N, int K) {
    __shared__ __align__(16) unsigned short As[128 * 64];
    __shared__ __align__(16) unsigned short Bs[128 * 64];
    const int tid = threadIdx.x;
    const int w = tid >> 6, lane = tid & 63;
    const int l31 = lane & 31, lhi = lane >> 5;
    const int m0 = blockIdx.y * 128, n0 = blockIdx.x * 128;
    const int wm = (w & 1) * 64, wn = (w >> 1) * 64;

    f32x16 acc[2][2];
#pragma unroll
    for (int a = 0; a < 2; ++a)
#pragma unroll
        for (int b = 0; b < 2; ++b)
#pragma unroll
            for (int r = 0; r < 16; ++r) acc[a][b][r] = 0.f;

    const int gsw = (l31 & 7) ^ ((l31 >> 2) & 6);

    for (int k0 = 0; k0 < K; k0 += 64) {
#pragma unroll
        for (int j = 0; j < 4; ++j) {
            int c   = (w * 4 + j) * 64 + lane;   // chunk id 0..1023
            int row = c >> 3;
            int kcg = (c & 7) ^ (row & 7) ^ ((row >> 2) & 6);  // swizzled source chunk
            async_load16(A  + (size_t)(m0 + row) * K + k0 + kcg * 8,
                         As + (size_t)(w * 4 + j) * 64 * 8);
            async_load16(BT + (size_t)(n0 + row) * K + k0 + kcg * 8,
                         Bs + (size_t)(w * 4 + j) * 64 * 8);
        }
        __syncthreads();   // drains vmcnt for global_load_lds
#pragma unroll
        for (int ks = 0; ks < 4; ++ks) {         // 4 k-steps of 16
            short8 af[2], bfr[2];
#pragma unroll
            for (int mt = 0; mt < 2; ++mt) {
                int row = wm + mt * 32 + l31;
                int kcs = (ks * 2 + lhi) ^ gsw;
                af[mt] = *(const short8*)(As + row * 64 + kcs * 8);
            }
#pragma unroll
            for (int nt = 0; nt < 2; ++nt) {
                int row = wn + nt * 32 + l31;
                int kcs = (ks * 2 + lhi) ^ gsw;
                bfr[nt] = *(const short8*)(Bs + row * 64 + kcs * 8);
            }
#pragma unroll
            for (int mt = 0; mt < 2; ++mt)
#pragma unroll
                for (int nt = 0; nt < 2; ++nt)
                    acc[mt][nt] = __builtin_amdgcn_mfma_f32_32x32x16_bf16(
                        af[mt], bfr[nt], acc[mt][nt], 0, 0, 0);
        }
        __syncthreads();
    }

    if (MODE == 0) {
#pragma unroll
        for (int mt = 0; mt < 2; ++mt)
#pragma unroll
            for (int nt = 0; nt < 2; ++nt)
#pragma unroll
                for (int r = 0; r < 16; ++r) {
                    int row = m0 + wm + mt * 32 + (r & 3) + 8 * (r >> 2) + 4 * lhi;
                    int col = n0 + wn + nt * 32 + l31;
                    Cout[(size_t)row * N + col] = acc[mt][nt][r];
                }
    } else {
        // qkv column -> head h = col/384; within-head: [0,128) q, [128,256) k,
        // [256,384) v. 32-col tiles never straddle sections (128 % 32 == 0).
#pragma unroll
        for (int mt = 0; mt < 2; ++mt) {
            int trowb = m0 + wm + mt * 32;      // 32-row tile, within one batch
            int bi = trowb >> 11;
            int tb = trowb & (T_SEQ - 1);
#pragma unroll
            for (int nt = 0; nt < 2; ++nt) {
                int colb = n0 + wn + nt * 32;
                int h    = colb / 384;
                int r3   = colb - h * 384;
                int sec  = r3 >> 7;
                int dk   = (r3 & 127) + l31;
                if (sec < 2) {
                    unsigned short* dst = (sec == 0 ? qraw : kraw) +
                        ((size_t)(bi * NH + h) * T_SEQ + tb) * DK + dk;
#pragma unroll
                    for (int r = 0; r < 16; ++r) {
                        int t = (r & 3) + 8 * (r >> 2) + 4 * lhi;
                        dst[(size_t)t * DK] = f2bf(acc[mt][nt][r]);
                    }
                } else {
                    // V stored transposed (B,H,DK,T): regs 4g..4g+3 are 4
                    // consecutive t -> one 8B store per group
                    unsigned short* dst =
                        vtb + ((size_t)(bi * NH + h) * DK + dk) * T_SEQ + tb;
#pragma unroll
                    for (int g = 0; g < 4; ++g) {
                        ushort4 p;
                        p.x = f2bf(acc[mt][nt][4 * g + 0]);
                        p.y = f2bf(acc[mt][nt][4 * g + 1]);
                        p.z = f2bf(acc[mt][nt][4 * g + 2]);
                        p.w = f2bf(acc[mt][nt][4 * g + 3]);
                        *(ushort4*)(dst + 8 * g + 4 * lhi) = p;
                    }
                }
            }
        }
    }
}

// ---------------------------------------------------------------- RoPE (in place)
__global__ void rope_kernel(unsigned short* __restrict__ qraw,
                            unsigned short* __restrict__ kraw,
                            const float* __restrict__ freqs) {
    int linear = blockIdx.x * 256 + threadIdx.x;   // ((b*NH+h)*T + t)*64 + i
    int i  = linear & 63;
    int t  = (linear >> 6) & (T_SEQ - 1);
    int bh = linear >> 17;
    int b  = bh >> 4;
    float f  = freqs[((size_t)b * T_SEQ + t) * 64 + i];
    float cs = __cosf(f), sn = __sinf(f);
    size_t off = ((size_t)bh * T_SEQ + t) * DK + 2 * i;
    ushort2 qp = *(ushort2*)(qraw + off);
    ushort2 kp = *(ushort2*)(kraw + off);
    float qr = bf2f(qp.x), qi = bf2f(qp.y);
    float kr = bf2f(kp.x), ki = bf2f(kp.y);
    ushort2 qo, ko;
    qo.x = f2bf(qr * cs - qi * sn); qo.y = f2bf(qr * sn + qi * cs);
    ko.x = f2bf(kr * cs - ki * sn); ko.y = f2bf(kr * sn + ki * cs);
    *(ushort2*)(qraw + off) = qo;
    *(ushort2*)(kraw + off) = ko;
}

// ---------------------------------------------------------------- flash attention
// Round-7: 2x2 wave split over (q-rows x keys). Block = 64 q-rows (grid and
// load balance identical to the 110us round-5 version). Wave (wq,wk) owns
// q-rows [32wq,32wq+32) and keys [32wk,32wk+32) of each KV tile:
//   K reads/wave 16->8 (its key half; each bk feeds both q-subtiles),
//   V reads/wave 16->8 (its key chunks), ap 2. LDS b128/wave/iter 34->18 —
//   attacks the measured LDS-read bound (~4200 cy LDS vs 1320 MFMA per CU-iter).
// Fixed-M softmax makes the key split exact with NO per-tile cross-wave
// traffic: numerators local, l and O are linear accumulators -> single LDS
// reduction over wk at the epilogue (reuses Ks as 32KB f32 scratch).
// pbuf per-wave 32x36 (quad step = 288B = 8 banks mod 32 -> disjoint octets,
// conflict-free writes; reads span even banks like the proven stride-68).
__global__ __launch_bounds__(256) void attn_kernel(
    const unsigned short* __restrict__ qb, const unsigned short* __restrict__ kb,
    const unsigned short* __restrict__ vt, unsigned short* __restrict__ ctx) {
    __shared__ __align__(16) unsigned short Ks[2][64 * 128];   // [key][dk]   2x16 KB
    __shared__ __align__(16) unsigned short Vs[2][128 * 64];   // [dk][key]   2x16 KB
    __shared__ __align__(16) unsigned short pbuf[4][32 * 36];  // 9 KB
    const int qt   = 31 - blockIdx.y;               // heavy tiles dispatched first
    const int u    = blockIdx.x;
    const int bh   = ((u & 7) << 2) | (u >> 3);     // same head -> same XCD (id%8)
    const int q0   = qt * 64;
    const int w    = threadIdx.x >> 6, lane = threadIdx.x & 63;
    const int lrow = lane & 15, quad = lane >> 4;
    const int wq = w >> 1, wk = w & 1;
    const float sc2 = 0.08838834764831845f * 1.4426950408889634f;  // DK^-.5 * log2e
    const short8 vone = {16256, 16256, 16256, 16256, 16256, 16256, 16256, 16256}; // bf16 1.0

    // Q A-frags: 2 q-subtiles of 16 rows (A[m=lane&15][k=quad*8+j])
    short8 aq[2][4];
#pragma unroll
    for (int g = 0; g < 2; ++g) {
        const unsigned short* qbase =
            qb + ((size_t)bh * T_SEQ + q0 + 32 * wq + 16 * g + lrow) * DK;
#pragma unroll
        for (int kk = 0; kk < 4; ++kk)
            aq[g][kk] = *(const short8*)(qbase + kk * 32 + quad * 8);
    }

    f32x4 o[2][8];
#pragma unroll
    for (int g = 0; g < 2; ++g)
#pragma unroll
        for (int d = 0; d < 8; ++d) o[g][d] = (f32x4){0.f, 0.f, 0.f, 0.f};
    f32x4 ol[2];
    ol[0] = (f32x4){0.f, 0.f, 0.f, 0.f};
    ol[1] = (f32x4){0.f, 0.f, 0.f, 0.f};

    const unsigned short* kg0 = kb + (size_t)bh * T_SEQ * DK;
    const unsigned short* vg0 = vt + (size_t)bh * DK * T_SEQ;

    auto stage = [&](int kt, int sbuf) {
        const unsigned short* kg = kg0 + (size_t)kt * 64 * DK;
        const unsigned short* vg = vg0 + kt * 64;
        unsigned short* Kd = &Ks[sbuf][0];
        unsigned short* Vd = &Vs[sbuf][0];
#pragma unroll
        for (int j = 0; j < 4; ++j) {
            int c = (w * 4 + j) * 64 + lane;            // 0..1023
            int kr_ = c >> 4, kc = (c & 15) ^ (kr_ & 7);
            async_load16(kg + (size_t)kr_ * DK + kc * 8, Kd + c * 8);
            int vr = c >> 3, vc = (c & 7) ^ (vr & 7);
            async_load16(vg + (size_t)vr * T_SEQ + vc * 8, Vd + c * 8);
        }
    };

    stage(0, 0);
    for (int kt = 0; kt <= qt; ++kt) {
        __syncthreads();   // drains own vmcnt (incl. stage(kt)) then syncs waves
        if (kt < qt) stage(kt + 1, (kt + 1) & 1);
        const unsigned short* Kb = &Ks[kt & 1][0];
        const unsigned short* Vb = &Vs[kt & 1][0];

        // ---- S = Q K^T : 32 q-rows x 32 keys per wave; bk read once per
        // (kk,kt2), used for both q-subtiles
        f32x4 s[2][2];
#pragma unroll
        for (int g = 0; g < 2; ++g)
#pragma unroll
            for (int kt2 = 0; kt2 < 2; ++kt2) s[g][kt2] = (f32x4){0.f, 0.f, 0.f, 0.f};
#pragma unroll
        for (int kk = 0; kk < 4; ++kk)
#pragma unroll
            for (int kt2 = 0; kt2 < 2; ++kt2) {
                int row = 32 * wk + kt2 * 16 + lrow;
                int kc = (kk * 4 + quad) ^ (row & 7);
                short8 bk = *(const short8*)(Kb + row * 128 + kc * 8);
                s[0][kt2] = __builtin_amdgcn_mfma_f32_16x16x32_bf16(
                    aq[0][kk], bk, s[0][kt2], 0, 0, 0);
                s[1][kt2] = __builtin_amdgcn_mfma_f32_16x16x32_bf16(
                    aq[1][kk], bk, s[1][kt2], 0, 0, 0);
            }

        // ---- fixed-M softmax numerator: p = 2^(s*sc2 - 12); causal on diag
        const bool diag = (kt == qt);
        unsigned short* pb = &pbuf[w][0];
#pragma unroll
        for (int g = 0; g < 2; ++g)
#pragma unroll
            for (int kt2 = 0; kt2 < 2; ++kt2)
#pragma unroll
                for (int r = 0; r < 4; ++r) {
                    float p = exp2f(fmaf(s[g][kt2][r], sc2, -12.0f));
                    if (diag && (32 * wk + kt2 * 16 + lrow >
                                 32 * wq + 16 * g + quad * 4 + r)) p = 0.f;
                    pb[(g * 16 + quad * 4 + r) * 36 + kt2 * 16 + lrow] = f2bf(p);
                }
        __builtin_amdgcn_s_waitcnt(0xc07f);  // lgkmcnt(0): P writes visible
        short8 ap[2];
#pragma unroll
        for (int g = 0; g < 2; ++g)
            ap[g] = *(const short8*)(pb + (16 * g + lrow) * 36 + quad * 8);

        // ---- O += P V over this wave's 32 keys ; l += P @ ones
#pragma unroll
        for (int g = 0; g < 2; ++g)
            ol[g] = __builtin_amdgcn_mfma_f32_16x16x32_bf16(ap[g], vone, ol[g], 0, 0, 0);
#pragma unroll
        for (int d = 0; d < 8; ++d) {
            int row = d * 16 + lrow;
            int vc = (wk * 4 + quad) ^ (row & 7);
            short8 bv = *(const short8*)(Vb + row * 64 + vc * 8);
            o[0][d] = __builtin_amdgcn_mfma_f32_16x16x32_bf16(ap[0], bv, o[0][d], 0, 0, 0);
            o[1][d] = __builtin_amdgcn_mfma_f32_16x16x32_bf16(ap[1], bv, o[1][d], 0, 0, 0);
        }
    }

    // ---- cross-wave (wk) reduction of partial O and l, then store.
    // No staging in flight; Ks is dead -> reuse as [2 wq][32 q][128 dk] f32.
    __syncthreads();
    float* red  = (float*)&Ks[0][0];    // 32 KB, exactly Ks[0]+Ks[1]
    float* redl = (float*)&pbuf[0][0];  // 64 floats
    if (wk == 1) {
#pragma unroll
        for (int g = 0; g < 2; ++g) {
#pragma unroll
            for (int d = 0; d < 8; ++d)
#pragma unroll
                for (int r = 0; r < 4; ++r)
                    red[(wq * 32 + g * 16 + quad * 4 + r) * 128 + d * 16 + lrow] =
                        o[g][d][r];
            if (lrow == 0)
#pragma unroll
                for (int r = 0; r < 4; ++r)
                    redl[wq * 32 + g * 16 + quad * 4 + r] = ol[g][r];
        }
    }
    __syncthreads();
    if (wk == 0) {
        const int b = bh >> 4, h = bh & 15;
#pragma unroll
        for (int g = 0; g < 2; ++g) {
            float rl[4];
#pragma unroll
            for (int r = 0; r < 4; ++r)
                rl[r] = 1.0f / (ol[g][r] + redl[wq * 32 + g * 16 + quad * 4 + r]);
#pragma unroll
            for (int d = 0; d < 8; ++d)
#pragma unroll
                for (int r = 0; r < 4; ++r) {
                    float v = o[g][d][r] +
                        red[(wq * 32 + g * 16 + quad * 4 + r) * 128 + d * 16 + lrow];
                    int row = q0 + 32 * wq + 16 * g + quad * 4 + r;
                    ctx[((size_t)(b * T_SEQ + row)) * DMODEL + h * DK + d * 16 + lrow] =
                        f2bf(v * rl[r]);
                }
        }
    }
}

// ---------------------------------------------------------------- launch
extern "C" void kernel_launch(void* const* d_in, const int* in_sizes, int n_in,
                              void* d_out, int out_size, void* d_ws, size_t ws_size,
                              hipStream_t stream) {
    const float* x     = (const float*)d_in[0];
    const float* freqs = (const float*)d_in[1];
    const float* Wqkv  = (const float*)d_in[2];
    const float* Wout  = (const float*)d_in[3];
    float* out = (float*)d_out;
    char* ws = (char*)d_ws;
    // workspace layout (96 MiB total); ctx aliases xb (dead after GEMM1)
    unsigned short* xb    = (unsigned short*)(ws);               // 16 MiB
    unsigned short* ctx   = (unsigned short*)(ws);               // 16 MiB (alias)
    unsigned short* wqkvT = (unsigned short*)(ws + 16777216);    // 24 MiB
    unsigned short* woutT = (unsigned short*)(ws + 41943040);    // 8 MiB
    unsigned short* qraw  = (unsigned short*)(ws + 50331648);    // 16 MiB
    unsigned short* kraw  = (unsigned short*)(ws + 67108864);    // 16 MiB
    unsigned short* vtb   = (unsigned short*)(ws + 83886080);    // 16 MiB

    cast_x_kernel<<<8192, 256, 0, stream>>>(x, xb, 2097152);
    wtrans_kernel<<<dim3(96, 32), 256, 0, stream>>>(Wqkv, wqkvT, DMODEL, NQKV);
    wtrans_kernel<<<dim3(32, 32), 256, 0, stream>>>(Wout, woutT, DMODEL, DMODEL);
    gemm_bt_kernel<1><<<dim3(48, 32), 256, 0, stream>>>(
        xb, wqkvT, nullptr, qraw, kraw, vtb, BATCH * T_SEQ, NQKV, DMODEL);
    rope_kernel<<<16384, 256, 0, stream>>>(qraw, kraw, freqs);
    attn_kernel<<<dim3(32, 32), 256, 0, stream>>>(qraw, kraw, vtb, ctx);
    gemm_bt_kernel<0><<<dim3(16, 32), 256, 0, stream>>>(
        ctx, woutT, out, nullptr, nullptr, nullptr, BATCH * T_SEQ, DMODEL, DMODEL);
}

// Round 8
// 380.322 us; speedup vs baseline: 1.0684x; 1.0232x over previous
//
#include <hip/hip_runtime.h>
#include <cstdint>

// Problem constants
#define BATCH   2
#define T_SEQ   2048
#define NH      16
#define DK      128
#define DMODEL  2048   // NH*DK
#define NQKV    6144   // 3*DMODEL

using short8 = __attribute__((ext_vector_type(8))) short;   // 8 bf16 (4 VGPRs)
using f32x4  = __attribute__((ext_vector_type(4))) float;   // 16x16 MFMA C/D
using f32x16 = __attribute__((ext_vector_type(16))) float;  // 32x32 MFMA C/D

__device__ __forceinline__ float bf2f(unsigned short u) {
    union { float f; uint32_t i; } x; x.i = ((uint32_t)u) << 16; return x.f;
}
__device__ __forceinline__ unsigned short f2bf(float f) {
    union { float f; uint32_t i; } x; x.f = f;
    uint32_t r = x.i + 0x7fffu + ((x.i >> 16) & 1u);   // RNE (no NaN inputs here)
    return (unsigned short)(r >> 16);
}

// async global->LDS, 16B per lane. LDS dest = wave-uniform base + lane*16 (m104/m108).
__device__ __forceinline__ void async_load16(const unsigned short* g, unsigned short* l) {
    __builtin_amdgcn_global_load_lds(
        (const __attribute__((address_space(1))) unsigned int*)g,
        (__attribute__((address_space(3))) unsigned int*)l,
        16, 0, 0);
}

// ---------------------------------------------------------------- prep kernels

__global__ void cast_x_kernel(const float* __restrict__ x,
                              unsigned short* __restrict__ xb, int n4) {
    int i = blockIdx.x * 256 + threadIdx.x;
    if (i >= n4) return;
    float4 v = ((const float4*)x)[i];
    ushort4 o;
    o.x = f2bf(v.x); o.y = f2bf(v.y); o.z = f2bf(v.z); o.w = f2bf(v.w);
    ((ushort4*)xb)[i] = o;
}

// W (K,N) fp32 row-major -> WT (N,K) bf16 row-major (for gemm_bt B-frag reads)
__global__ void wtrans_kernel(const float* __restrict__ W,
                              unsigned short* __restrict__ WT, int K, int N) {
    __shared__ unsigned short tile[64][65];  // +1 pad
    int k0 = blockIdx.y * 64, n0 = blockIdx.x * 64;
    for (int it = 0; it < 16; ++it) {
        int idx = it * 256 + threadIdx.x;
        int r = idx >> 6, c = idx & 63;                       // r: k-row, c: n-col
        tile[r][c] = f2bf(W[(size_t)(k0 + r) * N + n0 + c]);  // coalesced in n
    }
    __syncthreads();
    for (int it = 0; it < 16; ++it) {
        int idx = it * 256 + threadIdx.x;
        int r = idx >> 6, c = idx & 63;                       // r: n-row of WT, c: k-col
        WT[(size_t)(n0 + r) * K + k0 + c] = tile[c][r];       // coalesced in k
    }
}

// ---------------------------------------------------------------- GEMM
// 128x128 tile, BK=64, 4 waves 2x2, 32x32x16 MFMA, 32 KiB LDS -> 3 blocks/CU
// (implicit wave-overlap, m114). At the m97-structure ceiling (~873 TF).
// SQ_LDS_BANK_CONFLICT = 4.0/ds_read_b128 is structural to the l31-row read
// shape (invariant to slot permutation, r5) — accepted (~5us).
template <int MODE>
__global__ __launch_bounds__(256) void gemm_bt_kernel(
    const unsigned short* __restrict__ A, const unsigned short* __restrict__ BT,
    float* __restrict__ Cout,
    unsigned short* __restrict__ qraw, unsigned short* __restrict__ kraw,
    unsigned short* __restrict__ vtb,
    int M, int N, int K) {
    __shared__ __align__(16) unsigned short As[128 * 64];
    __shared__ __align__(16) unsigned short Bs[128 * 64];
    const int tid = threadIdx.x;
    const int w = tid >> 6, lane = tid & 63;
    const int l31 = lane & 31, lhi = lane >> 5;
    const int m0 = blockIdx.y * 128, n0 = blockIdx.x * 128;
    const int wm = (w & 1) * 64, wn = (w >> 1) * 64;

    f32x16 acc[2][2];
#pragma unroll
    for (int a = 0; a < 2; ++a)
#pragma unroll
        for (int b = 0; b < 2; ++b)
#pragma unroll
            for (int r = 0; r < 16; ++r) acc[a][b][r] = 0.f;

    const int gsw = (l31 & 7) ^ ((l31 >> 2) & 6);

    for (int k0 = 0; k0 < K; k0 += 64) {
#pragma unroll
        for (int j = 0; j < 4; ++j) {
            int c   = (w * 4 + j) * 64 + lane;   // chunk id 0..1023
            int row = c >> 3;
            int kcg = (c & 7) ^ (row & 7) ^ ((row >> 2) & 6);  // swizzled source chunk
            async_load16(A  + (size_t)(m0 + row) * K + k0 + kcg * 8,
                         As + (size_t)(w * 4 + j) * 64 * 8);
            async_load16(BT + (size_t)(n0 + row) * K + k0 + kcg * 8,
                         Bs + (size_t)(w * 4 + j) * 64 * 8);
        }
        __syncthreads();   // drains vmcnt for global_load_lds
#pragma unroll
        for (int ks = 0; ks < 4; ++ks) {         // 4 k-steps of 16
            short8 af[2], bfr[2];
#pragma unroll
            for (int mt = 0; mt < 2; ++mt) {
                int row = wm + mt * 32 + l31;
                int kcs = (ks * 2 + lhi) ^ gsw;
                af[mt] = *(const short8*)(As + row * 64 + kcs * 8);
            }
#pragma unroll
            for (int nt = 0; nt < 2; ++nt) {
                int row = wn + nt * 32 + l31;
                int kcs = (ks * 2 + lhi) ^ gsw;
                bfr[nt] = *(const short8*)(Bs + row * 64 + kcs * 8);
            }
#pragma unroll
            for (int mt = 0; mt < 2; ++mt)
#pragma unroll
                for (int nt = 0; nt < 2; ++nt)
                    acc[mt][nt] = __builtin_amdgcn_mfma_f32_32x32x16_bf16(
                        af[mt], bfr[nt], acc[mt][nt], 0, 0, 0);
        }
        __syncthreads();
    }

    if (MODE == 0) {
#pragma unroll
        for (int mt = 0; mt < 2; ++mt)
#pragma unroll
            for (int nt = 0; nt < 2; ++nt)
#pragma unroll
                for (int r = 0; r < 16; ++r) {
                    int row = m0 + wm + mt * 32 + (r & 3) + 8 * (r >> 2) + 4 * lhi;
                    int col = n0 + wn + nt * 32 + l31;
                    Cout[(size_t)row * N + col] = acc[mt][nt][r];
                }
    } else {
        // qkv column -> head h = col/384; within-head: [0,128) q, [128,256) k,
        // [256,384) v. 32-col tiles never straddle sections (128 % 32 == 0).
#pragma unroll
        for (int mt = 0; mt < 2; ++mt) {
            int trowb = m0 + wm + mt * 32;      // 32-row tile, within one batch
            int bi = trowb >> 11;
            int tb = trowb & (T_SEQ - 1);
#pragma unroll
            for (int nt = 0; nt < 2; ++nt) {
                int colb = n0 + wn + nt * 32;
                int h    = colb / 384;
                int r3   = colb - h * 384;
                int sec  = r3 >> 7;
                int dk   = (r3 & 127) + l31;
                if (sec < 2) {
                    unsigned short* dst = (sec == 0 ? qraw : kraw) +
                        ((size_t)(bi * NH + h) * T_SEQ + tb) * DK + dk;
#pragma unroll
                    for (int r = 0; r < 16; ++r) {
                        int t = (r & 3) + 8 * (r >> 2) + 4 * lhi;
                        dst[(size_t)t * DK] = f2bf(acc[mt][nt][r]);
                    }
                } else {
                    // V stored transposed (B,H,DK,T): regs 4g..4g+3 are 4
                    // consecutive t -> one 8B store per group
                    unsigned short* dst =
                        vtb + ((size_t)(bi * NH + h) * DK + dk) * T_SEQ + tb;
#pragma unroll
                    for (int g = 0; g < 4; ++g) {
                        ushort4 p;
                        p.x = f2bf(acc[mt][nt][4 * g + 0]);
                        p.y = f2bf(acc[mt][nt][4 * g + 1]);
                        p.z = f2bf(acc[mt][nt][4 * g + 2]);
                        p.w = f2bf(acc[mt][nt][4 * g + 3]);
                        *(ushort4*)(dst + 8 * g + 4 * lhi) = p;
                    }
                }
            }
        }
    }
}

// ---------------------------------------------------------------- RoPE (in place)
__global__ void rope_kernel(unsigned short* __restrict__ qraw,
                            unsigned short* __restrict__ kraw,
                            const float* __restrict__ freqs) {
    int linear = blockIdx.x * 256 + threadIdx.x;   // ((b*NH+h)*T + t)*64 + i
    int i  = linear & 63;
    int t  = (linear >> 6) & (T_SEQ - 1);
    int bh = linear >> 17;
    int b  = bh >> 4;
    float f  = freqs[((size_t)b * T_SEQ + t) * 64 + i];
    float cs = __cosf(f), sn = __sinf(f);
    size_t off = ((size_t)bh * T_SEQ + t) * DK + 2 * i;
    ushort2 qp = *(ushort2*)(qraw + off);
    ushort2 kp = *(ushort2*)(kraw + off);
    float qr = bf2f(qp.x), qi = bf2f(qp.y);
    float kr = bf2f(kp.x), ki = bf2f(kp.y);
    ushort2 qo, ko;
    qo.x = f2bf(qr * cs - qi * sn); qo.y = f2bf(qr * sn + qi * cs);
    ko.x = f2bf(kr * cs - ki * sn); ko.y = f2bf(kr * sn + ki * cs);
    *(ushort2*)(qraw + off) = qo;
    *(ushort2*)(kraw + off) = ko;
}

// ---------------------------------------------------------------- flash attention
// Round-8: round-5 compute structure (best measured) + counted-vmcnt
// two-barrier pipeline (no vmcnt(0)/lgkmcnt(0) drain per iter) + setprio
// around MFMA clusters (m191: attn regime, independent blocks at
// different phases).
// Pipeline ledger (8 loads per stage, 2 tiles deep):
//   prologue: stage(0), stage(1)              -> outstanding {0,1}
//   iter kt:  kt<qt ? vmcnt(8) : vmcnt(0)     -> retires tile kt (FIFO)
//             s_barrier                        -> all waves' tile-kt in LDS
//             compute(buf kt&1)                (ds-read results consumed
//                                               before barrier -> complete)
//             s_barrier                        -> all waves done READING buf
//             if (kt+2 <= qt) stage(kt+2, kt&1)  (WAR-safe by barrier #2)
// At next top: outstanding {kt+1, kt+2} = 16 -> vmcnt(8) retires kt+1. OK.
__global__ __launch_bounds__(256) void attn_kernel(
    const unsigned short* __restrict__ qb, const unsigned short* __restrict__ kb,
    const unsigned short* __restrict__ vt, unsigned short* __restrict__ ctx) {
    __shared__ __align__(16) unsigned short Ks[2][64 * 128];   // [key][dk]   2x16 KB
    __shared__ __align__(16) unsigned short Vs[2][128 * 64];   // [dk][key]   2x16 KB
    __shared__ __align__(16) unsigned short pbuf[4][16 * 68];  // stride 68: 2-way banks
    const int qt   = 31 - blockIdx.y;               // heavy tiles dispatched first
    const int u    = blockIdx.x;
    const int bh   = ((u & 7) << 2) | (u >> 3);     // same head -> same XCD (id%8)
    const int q0   = qt * 64;
    const int w    = threadIdx.x >> 6, lane = threadIdx.x & 63;
    const int lrow = lane & 15, quad = lane >> 4;
    const int qrow = q0 + w * 16;
    const float sc2 = 0.08838834764831845f * 1.4426950408889634f;  // DK^-.5 * log2e
    const short8 vone = {16256, 16256, 16256, 16256, 16256, 16256, 16256, 16256}; // bf16 1.0

    // Q A-frags (A[m=lane&15][k=quad*8+j], k-chunks of 32 over DK=128)
    short8 aq[4];
    const unsigned short* qbase = qb + ((size_t)bh * T_SEQ + qrow + lrow) * DK;
#pragma unroll
    for (int kk = 0; kk < 4; ++kk)
        aq[kk] = *(const short8*)(qbase + kk * 32 + quad * 8);

    f32x4 o[8];
#pragma unroll
    for (int d = 0; d < 8; ++d) o[d] = (f32x4){0.f, 0.f, 0.f, 0.f};
    f32x4 ol = (f32x4){0.f, 0.f, 0.f, 0.f};   // row sums of P (denominator)

    const unsigned short* kg0 = kb + (size_t)bh * T_SEQ * DK;
    const unsigned short* vg0 = vt + (size_t)bh * DK * T_SEQ;

    auto stage = [&](int kt, int sbuf) {
        const unsigned short* kg = kg0 + (size_t)kt * 64 * DK;
        const unsigned short* vg = vg0 + kt * 64;
        unsigned short* Kd = &Ks[sbuf][0];
        unsigned short* Vd = &Vs[sbuf][0];
#pragma unroll
        for (int j = 0; j < 4; ++j) {
            int c = (w * 4 + j) * 64 + lane;            // 0..1023
            int kr_ = c >> 4, kc = (c & 15) ^ (kr_ & 7);
            async_load16(kg + (size_t)kr_ * DK + kc * 8, Kd + c * 8);
            int vr = c >> 3, vc = (c & 7) ^ (vr & 7);
            async_load16(vg + (size_t)vr * T_SEQ + vc * 8, Vd + c * 8);
        }
    };

    stage(0, 0);
    if (qt >= 1) stage(1, 1);
    for (int kt = 0; kt <= qt; ++kt) {
        if (kt < qt) { asm volatile("s_waitcnt vmcnt(8)" ::: "memory"); }
        else         { asm volatile("s_waitcnt vmcnt(0)" ::: "memory"); }
        __builtin_amdgcn_s_barrier();
        const unsigned short* Kb = &Ks[kt & 1][0];
        const unsigned short* Vb = &Vs[kt & 1][0];

        // ---- S = Q K^T (16x64 per wave)
        f32x4 s[4];
#pragma unroll
        for (int nt = 0; nt < 4; ++nt) s[nt] = (f32x4){0.f, 0.f, 0.f, 0.f};
        __builtin_amdgcn_s_setprio(1);
#pragma unroll
        for (int kk = 0; kk < 4; ++kk)
#pragma unroll
            for (int nt = 0; nt < 4; ++nt) {
                int row = nt * 16 + lrow;
                int kc = (kk * 4 + quad) ^ (row & 7);
                short8 bk = *(const short8*)(Kb + row * 128 + kc * 8);
                s[nt] = __builtin_amdgcn_mfma_f32_16x16x32_bf16(aq[kk], bk, s[nt], 0, 0, 0);
            }
        __builtin_amdgcn_s_setprio(0);

        // ---- fixed-M softmax numerator: p = 2^(s*sc2 - 12); causal zero on diag
        const bool diag = (kt == qt);
        unsigned short* pb = &pbuf[w][0];
#pragma unroll
        for (int nt = 0; nt < 4; ++nt)
#pragma unroll
            for (int r = 0; r < 4; ++r) {
                float p = exp2f(fmaf(s[nt][r], sc2, -12.0f));
                if (diag && (nt * 16 + lrow > w * 16 + quad * 4 + r)) p = 0.f;
                pb[(quad * 4 + r) * 68 + nt * 16 + lrow] = f2bf(p);
            }
        __builtin_amdgcn_s_waitcnt(0xc07f);  // lgkmcnt(0): P writes visible
        short8 ap[2];
#pragma unroll
        for (int kk2 = 0; kk2 < 2; ++kk2)
            ap[kk2] = *(const short8*)(pb + lrow * 68 + kk2 * 32 + quad * 8);

        // ---- O += P V ; l += P @ ones
        __builtin_amdgcn_s_setprio(1);
#pragma unroll
        for (int kk2 = 0; kk2 < 2; ++kk2)
            ol = __builtin_amdgcn_mfma_f32_16x16x32_bf16(ap[kk2], vone, ol, 0, 0, 0);
#pragma unroll
        for (int d = 0; d < 8; ++d)
#pragma unroll
            for (int kk2 = 0; kk2 < 2; ++kk2) {
                int row = d * 16 + lrow;
                int vc = (kk2 * 4 + quad) ^ (row & 7);
                short8 bv = *(const short8*)(Vb + row * 64 + vc * 8);
                o[d] = __builtin_amdgcn_mfma_f32_16x16x32_bf16(ap[kk2], bv, o[d], 0, 0, 0);
            }
        __builtin_amdgcn_s_setprio(0);

        __builtin_amdgcn_s_barrier();        // all waves done reading buf kt&1
        if (kt + 2 <= qt) stage(kt + 2, kt & 1);
    }

    // epilogue: ctx (b, t, h*DK+dk) bf16 ; divide by row sum (shift cancels)
    const int b = bh >> 4, h = bh & 15;
    float rl[4];
#pragma unroll
    for (int r = 0; r < 4; ++r) rl[r] = 1.0f / ol[r];
#pragma unroll
    for (int d = 0; d < 8; ++d)
#pragma unroll
        for (int r = 0; r < 4; ++r) {
            int row = qrow + quad * 4 + r;
            ctx[((size_t)(b * T_SEQ + row)) * DMODEL + h * DK + d * 16 + lrow] =
                f2bf(o[d][r] * rl[r]);
        }
}

// ---------------------------------------------------------------- launch
extern "C" void kernel_launch(void* const* d_in, const int* in_sizes, int n_in,
                              void* d_out, int out_size, void* d_ws, size_t ws_size,
                              hipStream_t stream) {
    const float* x     = (const float*)d_in[0];
    const float* freqs = (const float*)d_in[1];
    const float* Wqkv  = (const float*)d_in[2];
    const float* Wout  = (const float*)d_in[3];
    float* out = (float*)d_out;
    char* ws = (char*)d_ws;
    // workspace layout (96 MiB total); ctx aliases xb (dead after GEMM1)
    unsigned short* xb    = (unsigned short*)(ws);               // 16 MiB
    unsigned short* ctx   = (unsigned short*)(ws);               // 16 MiB (alias)
    unsigned short* wqkvT = (unsigned short*)(ws + 16777216);    // 24 MiB
    unsigned short* woutT = (unsigned short*)(ws + 41943040);    // 8 MiB
    unsigned short* qraw  = (unsigned short*)(ws + 50331648);    // 16 MiB
    unsigned short* kraw  = (unsigned short*)(ws + 67108864);    // 16 MiB
    unsigned short* vtb   = (unsigned short*)(ws + 83886080);    // 16 MiB

    cast_x_kernel<<<8192, 256, 0, stream>>>(x, xb, 2097152);
    wtrans_kernel<<<dim3(96, 32), 256, 0, stream>>>(Wqkv, wqkvT, DMODEL, NQKV);
    wtrans_kernel<<<dim3(32, 32), 256, 0, stream>>>(Wout, woutT, DMODEL, DMODEL);
    gemm_bt_kernel<1><<<dim3(48, 32), 256, 0, stream>>>(
        xb, wqkvT, nullptr, qraw, kraw, vtb, BATCH * T_SEQ, NQKV, DMODEL);
    rope_kernel<<<16384, 256, 0, stream>>>(qraw, kraw, freqs);
    attn_kernel<<<dim3(32, 32), 256, 0, stream>>>(qraw, kraw, vtb, ctx);
    gemm_bt_kernel<0><<<dim3(16, 32), 256, 0, stream>>>(
        ctx, woutT, out, nullptr, nullptr, nullptr, BATCH * T_SEQ, DMODEL, DMODEL);
}